// Round 8
// baseline (29332.370 us; speedup 1.0000x reference)
//
#include <hip/hip_runtime.h>
#include <cstdint>
#include <cstddef>

typedef unsigned short u16;
typedef unsigned int u32;
typedef _Float16 f16;
typedef __attribute__((ext_vector_type(8))) _Float16 f16x8;  // 8 fp16 (4 VGPRs)
typedef __attribute__((ext_vector_type(4))) float f32x4;     // MFMA 16x16 accumulator

__device__ inline f16 f2h(float f){ return (f16)f; }         // RNE cast
__device__ inline float h2f(f16 h){ return (float)h; }
__device__ inline float sigm(float x){ return 1.f / (1.f + __expf(-x)); }
__device__ inline float tanh_f(float x){ return 1.f - 2.f / (__expf(2.f * x) + 1.f); }

__device__ inline void gload_lds16(const void* g, void* l){
  __builtin_amdgcn_global_load_lds((const __attribute__((address_space(1))) u32*)g,
                                   (__attribute__((address_space(3))) u32*)l,
                                   16, 0, 0);
}

// ---------------- diagnostic: fill d_out with sentinel (ws too small) ----------------
__global__ __launch_bounds__(256) void fill_sentinel_k(float* __restrict__ out, int n){
  int i = blockIdx.x * 256 + threadIdx.x;
  if (i < n) out[i] = 1.0e9f;
}

// ---------------- init: zero h ping-pong buffers + flag slots ----------------
__global__ __launch_bounds__(256) void init_ws_k(u32* __restrict__ h0, u32* __restrict__ h1,
                                                 int* __restrict__ flags){
  int i = blockIdx.x * 256 + threadIdx.x;
  if (i < 32768){ h0[i] = 0u; h1[i] = 0u; }   // 2*64*512 fp16 = 32768 u32 each
  if (i < 512) flags[i] = 0;
}

// ---------------- convert/pad fp32 -> fp16 (also does the frame gather) ----------------
__global__ __launch_bounds__(256) void convert_pad_k(const float* __restrict__ src, f16* __restrict__ dst,
                              int dst_rows, int dst_cols, int src_rows, int src_cols,
                              int src_ld, int src_off){
  long long i = (long long)blockIdx.x * 256 + threadIdx.x;
  long long total = (long long)dst_rows * dst_cols;
  if (i >= total) return;
  int r = (int)(i / dst_cols), c = (int)(i % dst_cols);
  float v = 0.f;
  if (r < src_rows && c < src_cols) v = src[(long long)src_off + (long long)r * src_ld + c];
  dst[i] = f2h(v);
}

// ---------------- generic fp16 GEMM: out = act(A @ B^T + bias1 + bias2) ----------------
// A: M x K fp16 row-major (K % 32 == 0), B: N x K fp16 row-major.
// 128x128 tile, BK=32, 4 waves (2x2 of 64x64), global_load_lds staging with
// XOR swizzle ((r>>1)&3)<<4 on the 64B LDS rows (involution, verified).
// flags: bit0 = relu, bit1 = output fp16 (else fp32).
__global__ __launch_bounds__(256) void gemm_bt(
    const f16* __restrict__ A, const f16* __restrict__ B,
    const float* __restrict__ bias1, const float* __restrict__ bias2,
    void* __restrict__ outp, int M, int N, int K, int realN, int ldout, int flags)
{
  __shared__ f16 As[128 * 32];
  __shared__ f16 Bs[128 * 32];
  const int tid = threadIdx.x;
  const int w = tid >> 6, l = tid & 63;
  const int m0 = blockIdx.y << 7, n0 = blockIdx.x << 7;
  const int wm = w >> 1, wn = w & 1;

  f32x4 acc[4][4];
#pragma unroll
  for (int i = 0; i < 4; i++)
#pragma unroll
    for (int j = 0; j < 4; j++) acc[i][j] = f32x4{0.f, 0.f, 0.f, 0.f};

  for (int k0 = 0; k0 < K; k0 += 32) {
#pragma unroll
    for (int pass = 0; pass < 2; ++pass) {
      int chunk = pass * 256 + tid;            // 0..511 : 16B chunk of the 8KB tile
      int r = chunk >> 2;                      // tile row 0..127
      int cb = (chunk & 3) << 4;               // byte-in-64B-row
      int cbs = cb ^ (((r >> 1) & 3) << 4);    // pre-swizzled source byte
      gload_lds16(A + (size_t)(m0 + r) * K + k0 + (cbs >> 1),
                  (char*)As + pass * 4096 + w * 1024);
      gload_lds16(B + (size_t)(n0 + r) * K + k0 + (cbs >> 1),
                  (char*)Bs + pass * 4096 + w * 1024);
    }
    __syncthreads();

    f16x8 af[4], bfr[4];
#pragma unroll
    for (int i = 0; i < 4; i++) {
      int rr = (wm << 6) + (i << 4) + (l & 15);
      int cba = ((l >> 4) << 4) ^ (((rr >> 1) & 3) << 4);
      af[i] = *(const f16x8*)((const char*)As + rr * 64 + cba);
      int rr2 = (wn << 6) + (i << 4) + (l & 15);
      int cbb = ((l >> 4) << 4) ^ (((rr2 >> 1) & 3) << 4);
      bfr[i] = *(const f16x8*)((const char*)Bs + rr2 * 64 + cbb);
    }
#pragma unroll
    for (int i = 0; i < 4; i++)
#pragma unroll
      for (int j = 0; j < 4; j++)
        acc[i][j] = __builtin_amdgcn_mfma_f32_16x16x32_f16(af[i], bfr[j], acc[i][j], 0, 0, 0);
    __syncthreads();
  }

#pragma unroll
  for (int j = 0; j < 4; j++) {
    int gc = n0 + (wn << 6) + (j << 4) + (l & 15);
    float bb = 0.f;
    if (gc < realN) {
      if (bias1) bb += bias1[gc];
      if (bias2) bb += bias2[gc];
    }
#pragma unroll
    for (int i = 0; i < 4; i++) {
#pragma unroll
      for (int jj = 0; jj < 4; jj++) {
        int gr = m0 + (wm << 6) + (i << 4) + ((l >> 4) << 2) + jj;
        float v = acc[i][j][jj] + bb;
        if (flags & 1) v = fmaxf(v, 0.f);
        if (gc < realN) {
          if (flags & 2) ((f16*)outp)[(size_t)gr * ldout + gc] = f2h(v);
          else           ((float*)outp)[(size_t)gr * ldout + gc] = v;
        }
      }
    }
  }
}

// ---------------- sequential 2-layer LSTM scan (folded input projection) ----------------
// 128 blocks x 64 threads (1 wave each). Wave = (rt, ut): 16 batch rows x 16
// units, ALL FOUR gates per lane via 4 separate MFMA accumulators (B-fragment
// row = g*512 + unit). Phase A computes the LSTM-1 input projection in-scan:
// gates1 = b1i+b1h + z2rows@w1ih^T (K=1024) + h0_{t-1}@w1hh^T (K=512) -- no
// precomputed g1pre buffer (saves 128MB workspace + a 137GF GEMM).
// Lane (lr=l&15, lk=l>>4) owns unit u0+lr, rows r0+lk*4+{0..3}; c-state fp32
// in registers. Weights stream from L2 (~328KB/wave/step). Mapping
// ut=(b&7)*4+(b>>5), rt=(b>>3)&3 -> per XCD: 4 ut x 4 rt, weight footprint
// ~1.3MB/XCD/step (L2-hot, hidden under ~1600cyc MFMA issue).
// Sync: own-slot epoch flags, 32 slots per rt; producer release-stores t+1,
// consumers poll 32 slots with a 64-lane relaxed load + __all.
__global__ __launch_bounds__(64) void lstm_seq(
    const f16* __restrict__ z2,      // 32768 x 1024 fp16 (fc2 output)
    const f16* __restrict__ w1ih,    // 2048 x 1024 fp16
    const f16* __restrict__ w1hh,    // 2048 x 512 fp16
    const f16* __restrict__ w2ih,    // 2048 x 512 fp16
    const f16* __restrict__ w2hh,    // 2048 x 512 fp16
    const float* __restrict__ b1i, const float* __restrict__ b1h,
    const float* __restrict__ b2i, const float* __restrict__ b2h,
    f16* __restrict__ h0buf,         // 2 x 64 x 512 fp16 ping-pong
    f16* __restrict__ h1buf,         // 2 x 64 x 512 fp16 ping-pong
    f16* __restrict__ h1all,         // 32768 x 512 fp16 (all h1 states, feeds fc3)
    int* __restrict__ flags)         // h0 slots [rt][32] at 0, h1 slots at 128
{
  const int b  = blockIdx.x;
  const int ut = (b & 7) * 4 + (b >> 5);   // unit-tile 0..31 (XCD-local weight reuse)
  const int rt = (b >> 3) & 3;             // row-tile 0..3
  const int l  = threadIdx.x;
  const int r0 = rt << 4, u0 = ut << 4;
  const int lr = l & 15, lk = l >> 4;
  const int unit = u0 + lr;                // C/D layout: col = lane&15 -> unit
  const int ls = l & 31;                   // slot index this lane polls

  float c0[4] = {0.f, 0.f, 0.f, 0.f};
  float c1[4] = {0.f, 0.f, 0.f, 0.f};
  float bias1g[4], bias2g[4];
#pragma unroll
  for (int g = 0; g < 4; ++g) {
    bias1g[g] = b1i[g * 512 + unit] + b1h[g * 512 + unit];
    bias2g[g] = b2i[g * 512 + unit] + b2h[g * 512 + unit];
  }

  int* h0s = flags + rt * 32;
  int* h1s = flags + 128 + rt * 32;

  for (int t = 0; t < 512; ++t) {
    const int wb = t & 1, rb = wb ^ 1;
    const f16* h0r = h0buf + rb * (64 * 512);
    f16*       h0w = h0buf + wb * (64 * 512);
    const f16* h1r = h1buf + rb * (64 * 512);
    f16*       h1w = h1buf + wb * (64 * 512);

    // ---- Phase A: gates1 = biases + z2[t-rows] @ w1ih^T + h0_{t-1} @ w1hh^T ----
    f32x4 acc[4];
#pragma unroll
    for (int g = 0; g < 4; ++g) acc[g] = f32x4{bias1g[g], bias1g[g], bias1g[g], bias1g[g]};
    // input projection, K=1024
    const f16* zr = z2 + ((size_t)t * 64 + r0 + lr) * 1024;
#pragma unroll
    for (int kk = 0; kk < 32; ++kk) {
      f16x8 a = *(const f16x8*)(zr + kk * 32 + lk * 8);
#pragma unroll
      for (int g = 0; g < 4; ++g) {
        f16x8 bb = *(const f16x8*)(w1ih + (size_t)(g * 512 + unit) * 1024 + kk * 32 + lk * 8);
        acc[g] = __builtin_amdgcn_mfma_f32_16x16x32_f16(a, bb, acc[g], 0, 0, 0);
      }
    }
    // recurrent, K=512
#pragma unroll
    for (int kk = 0; kk < 16; ++kk) {
      f16x8 a = *(const f16x8*)(h0r + (r0 + lr) * 512 + kk * 32 + lk * 8);
#pragma unroll
      for (int g = 0; g < 4; ++g) {
        f16x8 bb = *(const f16x8*)(w1hh + (size_t)(g * 512 + unit) * 512 + kk * 32 + lk * 8);
        acc[g] = __builtin_amdgcn_mfma_f32_16x16x32_f16(a, bb, acc[g], 0, 0, 0);
      }
    }
    // cell 1 (c0 fp32 in registers)
#pragma unroll
    for (int j = 0; j < 4; ++j) {
      float i_ = sigm(acc[0][j]);
      float f_ = sigm(acc[1][j]);
      float g_ = tanh_f(acc[2][j]);
      float o_ = sigm(acc[3][j]);
      float c = f_ * c0[j] + i_ * g_;
      c0[j] = c;
      float h = o_ * tanh_f(c);
      h0w[(r0 + lk * 4 + j) * 512 + unit] = f2h(h);
    }
    // release h0_t (explicit fence + release store; waitcnt drains all lanes)
    __threadfence();
    if (l == 0) __hip_atomic_store(&h0s[ut], t + 1, __ATOMIC_RELEASE, __HIP_MEMORY_SCOPE_AGENT);

    // ---- Phase B part 1: acc2 = h1_{t-1} @ w2hh^T + biases (old data: cheap wait) ----
    for (;;) {
      int v = __hip_atomic_load(&h1s[ls], __ATOMIC_RELAXED, __HIP_MEMORY_SCOPE_AGENT);
      if (__all(v >= t)) break;
      __builtin_amdgcn_s_sleep(2);
    }
    __threadfence();                       // acquire for h1r
#pragma unroll
    for (int g = 0; g < 4; ++g) acc[g] = f32x4{bias2g[g], bias2g[g], bias2g[g], bias2g[g]};
#pragma unroll
    for (int kk = 0; kk < 16; ++kk) {
      f16x8 a = *(const f16x8*)(h1r + (r0 + lr) * 512 + kk * 32 + lk * 8);
#pragma unroll
      for (int g = 0; g < 4; ++g) {
        f16x8 bb = *(const f16x8*)(w2hh + (size_t)(g * 512 + unit) * 512 + kk * 32 + lk * 8);
        acc[g] = __builtin_amdgcn_mfma_f32_16x16x32_f16(a, bb, acc[g], 0, 0, 0);
      }
    }

    // ---- Phase B part 2: acc2 += h0_t @ w2ih^T (critical same-step sync) ----
    for (;;) {
      int v = __hip_atomic_load(&h0s[ls], __ATOMIC_RELAXED, __HIP_MEMORY_SCOPE_AGENT);
      if (__all(v >= t + 1)) break;
      __builtin_amdgcn_s_sleep(2);
    }
    __threadfence();                       // acquire for h0w
#pragma unroll
    for (int kk = 0; kk < 16; ++kk) {
      f16x8 a = *(const f16x8*)(h0w + (r0 + lr) * 512 + kk * 32 + lk * 8);
#pragma unroll
      for (int g = 0; g < 4; ++g) {
        f16x8 bb = *(const f16x8*)(w2ih + (size_t)(g * 512 + unit) * 512 + kk * 32 + lk * 8);
        acc[g] = __builtin_amdgcn_mfma_f32_16x16x32_f16(a, bb, acc[g], 0, 0, 0);
      }
    }
    // cell 2 (c1 fp32 in registers)
#pragma unroll
    for (int j = 0; j < 4; ++j) {
      float i_ = sigm(acc[0][j]);
      float f_ = sigm(acc[1][j]);
      float g_ = tanh_f(acc[2][j]);
      float o_ = sigm(acc[3][j]);
      float c = f_ * c1[j] + i_ * g_;
      c1[j] = c;
      float h = o_ * tanh_f(c);
      int row = r0 + lk * 4 + j;
      f16 hb = f2h(h);
      h1w[row * 512 + unit] = hb;
      h1all[((size_t)t * 64 + row) * 512 + unit] = hb;
    }
    __threadfence();
    if (l == 0) __hip_atomic_store(&h1s[ut], t + 1, __ATOMIC_RELEASE, __HIP_MEMORY_SCOPE_AGENT);
  }
}

// ---------------- host ----------------
extern "C" void kernel_launch(void* const* d_in, const int* in_sizes, int n_in,
                              void* d_out, int out_size, void* d_ws, size_t ws_size,
                              hipStream_t stream)
{
  const float* x      = (const float*)d_in[0];
  const float* fc1_w  = (const float*)d_in[1];
  const float* fc1_b  = (const float*)d_in[2];
  const float* fc2_w  = (const float*)d_in[3];
  const float* fc2_b  = (const float*)d_in[4];
  const float* l1_wih = (const float*)d_in[5];
  const float* l1_whh = (const float*)d_in[6];
  const float* l1_bih = (const float*)d_in[7];
  const float* l1_bhh = (const float*)d_in[8];
  const float* l2_wih = (const float*)d_in[9];
  const float* l2_whh = (const float*)d_in[10];
  const float* l2_bih = (const float*)d_in[11];
  const float* l2_bhh = (const float*)d_in[12];
  const float* fc3_w  = (const float*)d_in[13];
  const float* fc3_b  = (const float*)d_in[14];

  char* ws = (char*)d_ws;
  size_t off = 0;
  auto alloc = [&](size_t b){ size_t c = off; off += (b + 255) & ~(size_t)255; return c; };
  // static region: fp16 weights + h ping-pong + flags (~14 MB)
  f16* wfc1  = (f16*)(ws + alloc((size_t)1024 * 288 * 2));
  f16* wfc2  = (f16*)(ws + alloc((size_t)1024 * 1024 * 2));
  f16* w1ih  = (f16*)(ws + alloc((size_t)2048 * 1024 * 2));
  f16* w1hh  = (f16*)(ws + alloc((size_t)2048 * 512 * 2));
  f16* w2ih  = (f16*)(ws + alloc((size_t)2048 * 512 * 2));
  f16* w2hh  = (f16*)(ws + alloc((size_t)2048 * 512 * 2));
  f16* wfc3  = (f16*)(ws + alloc((size_t)384 * 512 * 2));
  f16* h0buf = (f16*)(ws + alloc((size_t)2 * 64 * 512 * 2));
  f16* h1buf = (f16*)(ws + alloc((size_t)2 * 64 * 512 * 2));
  int* flags = (int*)(ws + alloc(512 * 4));
  // dynamic region: 128 MB with liveness-based overlays
  //   xb    @ A+0     (18.9 MB, live conv->fc1)
  //   z1    @ A+64MB  (64 MB,   live fc1->fc2)
  //   z2    @ A+0     (64 MB,   live fc2->scan; overwrites dead xb)
  //   h1all @ A+64MB  (32 MB,   live scan->fc3; overwrites dead z1)
  size_t A = alloc((size_t)128 * 1024 * 1024);
  f16* xb    = (f16*)(ws + A);
  f16* z2    = (f16*)(ws + A);
  f16* z1    = (f16*)(ws + A + (size_t)64 * 1024 * 1024);
  f16* h1all = (f16*)(ws + A + (size_t)64 * 1024 * 1024);
  // total ~142 MB. If workspace is still too small: write a LOUD sentinel
  // (absmax ~1e9 identifies "ws too small" vs 5.535 "nothing ran").
  if (ws_size < off) {
    hipLaunchKernelGGL(fill_sentinel_k, dim3((out_size + 255) / 256), dim3(256), 0, stream,
                       (float*)d_out, out_size);
    return;
  }

  hipLaunchKernelGGL(init_ws_k, dim3(128), dim3(256), 0, stream,
                     (u32*)h0buf, (u32*)h1buf, flags);

  auto conv = [&](const float* src, f16* dst, int dr, int dc, int sr, int sc, int sld, int soff){
    long long total = (long long)dr * dc;
    hipLaunchKernelGGL(convert_pad_k, dim3((unsigned)((total + 255) / 256)), dim3(256), 0, stream,
                       src, dst, dr, dc, sr, sc, sld, soff);
  };
  // frame gather: x[:, 4, :] (mid = 7//2 + 1 = 4), pad K 257->288
  conv(x,      xb,   32768, 288, 32768, 257, 7 * 257, 4 * 257);
  conv(fc1_w,  wfc1, 1024,  288, 1024,  257, 257, 0);
  conv(fc2_w,  wfc2, 1024, 1024, 1024, 1024, 1024, 0);
  conv(l1_wih, w1ih, 2048, 1024, 2048, 1024, 1024, 0);
  conv(l1_whh, w1hh, 2048,  512, 2048,  512, 512, 0);
  conv(l2_wih, w2ih, 2048,  512, 2048,  512, 512, 0);
  conv(l2_whh, w2hh, 2048,  512, 2048,  512, 512, 0);
  conv(fc3_w,  wfc3,  384,  512,  257,  512, 512, 0);

  // z1 = xb @ fc1_w^T + fc1_b               (fp16 out)
  hipLaunchKernelGGL(gemm_bt, dim3(8, 256), dim3(256), 0, stream,
                     xb, wfc1, fc1_b, (const float*)nullptr, (void*)z1,
                     32768, 1024, 288, 1024, 1024, 2);
  // z2 = relu(z1 @ fc2_w^T + fc2_b)         (fp16 out)
  hipLaunchKernelGGL(gemm_bt, dim3(8, 256), dim3(256), 0, stream,
                     z1, wfc2, fc2_b, (const float*)nullptr, (void*)z2,
                     32768, 1024, 1024, 1024, 1024, 3);

  // sequential scan (cooperative; fall back to regular launch if coop fails --
  // 128 blocks x 64 threads is trivially co-resident on 256 CUs)
  {
    const f16* a0 = z2; const f16* a1 = w1ih; const f16* a2 = w1hh;
    const f16* a3 = w2ih; const f16* a4 = w2hh;
    const float* a5 = l1_bih; const float* a6 = l1_bhh;
    const float* a7 = l2_bih; const float* a8 = l2_bhh;
    f16* a9 = h0buf; f16* a10 = h1buf; f16* a11 = h1all; int* a12 = flags;
    void* args[] = {&a0, &a1, &a2, &a3, &a4, &a5, &a6, &a7, &a8, &a9, &a10, &a11, &a12};
    hipError_t ce = hipLaunchCooperativeKernel((const void*)lstm_seq, dim3(128), dim3(64),
                                               args, 0, stream);
    if (ce != hipSuccess) {
      hipLaunchKernelGGL(lstm_seq, dim3(128), dim3(64), 0, stream,
                         a0, a1, a2, a3, a4, a5, a6, a7, a8, a9, a10, a11, a12);
    }
  }

  // out = h1all @ fc3_w^T + fc3_b  (fp32 out, N padded to 384, write cols < 257)
  hipLaunchKernelGGL(gemm_bt, dim3(3, 256), dim3(256), 0, stream,
                     h1all, wfc3, fc3_b, (const float*)nullptr, d_out,
                     32768, 384, 512, 257, 257, 0);
  (void)in_sizes; (void)n_in; (void)out_size;
}